// Round 1
// 544.679 us; speedup vs baseline: 1.0255x; 1.0255x over previous
//
#include <hip/hip_runtime.h>

// PDP soft pruning mask on MI355X.
// N = 4096*16384 = 67108864 fp32 weights.
// t = 0.5*(Wh+Wt), Wh/Wt = (lim)th/(lim+1)th largest |w| (0-based, lim=6710885).
// out = w * sigmoid((w^2 - t^2)/0.01).
//
// R4 = R3 with a narrowed fine window + L3-aware apply pass.
//  1. 4M-element sample -> 4096-bin coarse hist (bits[30:19]). sigma_rank ~9.8K.
//  2. Second sample pass: 12288-bin fine hist (128-ulp bins) over the 3-coarse-bin
//     window -> locate t's fine bin kc in the sample; window2 = [kc-1024, kc+1024)
//     (~+-21 sigma bracket, 2048 bins -> 8 KB LDS instead of 48 KB).
//  3. ONE full pass: count elements above window2; 2048-bin LDS hist for elements
//     inside (full occupancy, 2-deep load ILP).
//  4. Scan -> 24-bit-prefix Wh,Wt (same 128-ulp lattice as R3 -> bit-identical t^2).
//  5. Apply pass: caching loads (input is L3-resident after pass 3), NT stores.

#define NBC  4096    // coarse bins (bits 30:19)
#define NBSF 12288   // sample fine bins: 3 coarse bins x 4096 (bits 18:7)
#define NBF2 2048    // full-pass fine bins (128-ulp), window2

typedef float    v4f __attribute__((ext_vector_type(4)));
typedef unsigned v4u __attribute__((ext_vector_type(4)));

__global__ void zero_ws(unsigned* __restrict__ ws, int n) {
    int i = blockIdx.x * blockDim.x + threadIdx.x;
    if (i < n) ws[i] = 0;
}

// 1024 blocks; block b histograms the first 4096 elements of its 65536-elem span.
__global__ void sample_hist(const v4u* __restrict__ in, unsigned* __restrict__ gh) {
    __shared__ unsigned h[NBC];
    for (int i = threadIdx.x; i < NBC; i += blockDim.x) h[i] = 0;
    __syncthreads();
    const v4u* p = in + (size_t)blockIdx.x * 16384;
    #pragma unroll
    for (int k = 0; k < 4; ++k) {
        v4u v = p[threadIdx.x + k * 256];
        atomicAdd(&h[(v.x & 0x7fffffffu) >> 19], 1u);
        atomicAdd(&h[(v.y & 0x7fffffffu) >> 19], 1u);
        atomicAdd(&h[(v.z & 0x7fffffffu) >> 19], 1u);
        atomicAdd(&h[(v.w & 0x7fffffffu) >> 19], 1u);
    }
    __syncthreads();
    for (int i = threadIdx.x; i < NBC; i += blockDim.x) {
        unsigned c = h[i];
        if (c) atomicAdd(&gh[i], c);
    }
}

// Find coarse bin of the sample's target quantile (from the top); emit [b_lo, b_hi].
__global__ void scan_sample(const unsigned* __restrict__ gh, unsigned* __restrict__ res,
                            unsigned sample_need) {
    __shared__ unsigned bins[NBC];      // descending-value order
    __shared__ unsigned part[256];
    __shared__ unsigned sup[16];
    unsigned s = 0;
    for (int j = 0; j < 16; ++j) {
        int idx = threadIdx.x * 16 + j;
        unsigned c = gh[NBC - 1 - idx];
        bins[idx] = c;
        s += c;
    }
    part[threadIdx.x] = s;
    __syncthreads();
    if (threadIdx.x < 16) {
        unsigned t = 0;
        for (int j = 0; j < 16; ++j) t += part[threadIdx.x * 16 + j];
        sup[threadIdx.x] = t;
    }
    __syncthreads();
    if (threadIdx.x == 0) {
        unsigned accum = 0; int sb = 15;
        for (int i = 0; i < 16; ++i) { unsigned nx = accum + sup[i]; if (nx >= sample_need) { sb = i; break; } accum = nx; }
        int pb = sb * 16 + 15;
        for (int i = sb * 16; i < sb * 16 + 16; ++i) { unsigned nx = accum + part[i]; if (nx >= sample_need) { pb = i; break; } accum = nx; }
        int d = pb * 16 + 15;
        for (int i = pb * 16; i < pb * 16 + 16; ++i) { unsigned nx = accum + bins[i]; if (nx >= sample_need) { d = i; break; } accum = nx; }
        unsigned b_est = (unsigned)(NBC - 1 - d);
        res[0] = (b_est > 0) ? b_est - 1u : 0u;                        // b_lo
        res[1] = (b_est < NBC - 1) ? b_est + 1u : (unsigned)(NBC - 1); // b_hi
    }
}

// Second sample pass: fine-histogram the SAME 4M sample inside the coarse window
// (128-ulp bins) and count sample elements above the window into res[4].
__global__ void sample_fine_hist(const v4u* __restrict__ in, unsigned* __restrict__ res,
                                 unsigned* __restrict__ gh) {
    __shared__ unsigned h[NBSF];
    __shared__ unsigned red[256];
    const unsigned lo = res[0] << 19;
    const unsigned hi = (res[1] + 1u) << 19;
    for (int i = threadIdx.x; i < NBSF; i += blockDim.x) h[i] = 0;
    __syncthreads();
    unsigned above = 0;
    const v4u* p = in + (size_t)blockIdx.x * 16384;
    #pragma unroll
    for (int k = 0; k < 4; ++k) {
        v4u v = p[threadIdx.x + k * 256];
        #pragma unroll
        for (int j = 0; j < 4; ++j) {
            unsigned u = v[j] & 0x7fffffffu;
            if (u >= hi) ++above;
            else if (u >= lo) atomicAdd(&h[(u - lo) >> 7], 1u);
        }
    }
    red[threadIdx.x] = above;
    __syncthreads();
    for (int s = 128; s > 0; s >>= 1) {
        if (threadIdx.x < (unsigned)s) red[threadIdx.x] += red[threadIdx.x + s];
        __syncthreads();
    }
    if (threadIdx.x == 0 && red[0]) atomicAdd(&res[4], red[0]);
    for (int i = threadIdx.x; i < NBSF; i += blockDim.x) {
        unsigned c = h[i];
        if (c) atomicAdd(&gh[i], c);
    }
}

// Locate t's fine bin kc within the coarse window from the sample ranks;
// emit window2 base key res[5] = clamp(kc - NBF2/2, 0, NBSF-NBF2).
// Sample sigma_rank ~9.8K ranks ~47 fine bins -> +-1024 bins is a ~21-sigma bracket.
__global__ void scan_sample2(const unsigned* __restrict__ gh, unsigned* __restrict__ res,
                             unsigned sample_need) {
    __shared__ unsigned bins[NBSF];     // descending-value order
    __shared__ unsigned part[256];
    __shared__ unsigned sup[16];
    unsigned s = 0;
    for (int j = 0; j < 48; ++j) {
        int idx = threadIdx.x * 48 + j;
        unsigned c = gh[NBSF - 1 - idx];
        bins[idx] = c;
        s += c;
    }
    part[threadIdx.x] = s;
    __syncthreads();
    if (threadIdx.x < 16) {
        unsigned t = 0;
        for (int j = 0; j < 16; ++j) t += part[threadIdx.x * 16 + j];
        sup[threadIdx.x] = t;
    }
    __syncthreads();
    if (threadIdx.x == 0) {
        unsigned accum = res[4];        // sample count above coarse window
        int sb = 15;
        for (int i = 0; i < 16; ++i) { unsigned nx = accum + sup[i]; if (nx >= sample_need) { sb = i; break; } accum = nx; }
        int pb = sb * 16 + 15;
        for (int i = sb * 16; i < sb * 16 + 16; ++i) { unsigned nx = accum + part[i]; if (nx >= sample_need) { pb = i; break; } accum = nx; }
        int d = pb * 48 + 47;
        for (int i = pb * 48; i < pb * 48 + 48; ++i) { unsigned nx = accum + bins[i]; if (nx >= sample_need) { d = i; break; } accum = nx; }
        int kc = NBSF - 1 - d;
        int kb = kc - (NBF2 / 2);
        if (kb < 0) kb = 0;
        if (kb > NBSF - NBF2) kb = NBSF - NBF2;
        res[5] = (unsigned)kb;
    }
}

// Full pass: count elements above window2 exactly; 2048-bin fine hist inside it.
// 8 KB LDS hist -> full occupancy; 2-deep load ILP.
__global__ void fine_hist(const v4u* __restrict__ in, unsigned* __restrict__ res,
                          unsigned* __restrict__ gh, int n4) {
    __shared__ unsigned h[NBF2];
    __shared__ unsigned red[256];
    const unsigned lo2 = (res[0] << 19) + (res[5] << 7);
    const unsigned hi2 = lo2 + ((unsigned)NBF2 << 7);
    for (int i = threadIdx.x; i < NBF2; i += blockDim.x) h[i] = 0;
    __syncthreads();
    unsigned above = 0;
    const int stride = gridDim.x * blockDim.x;
    int i = blockIdx.x * blockDim.x + threadIdx.x;
    for (; i + stride < n4; i += 2 * stride) {
        v4u a = in[i];
        v4u b = in[i + stride];
        #pragma unroll
        for (int k = 0; k < 4; ++k) {
            unsigned u = a[k] & 0x7fffffffu;
            if (u >= hi2) ++above;
            else if (u >= lo2) atomicAdd(&h[(u - lo2) >> 7], 1u);
        }
        #pragma unroll
        for (int k = 0; k < 4; ++k) {
            unsigned u = b[k] & 0x7fffffffu;
            if (u >= hi2) ++above;
            else if (u >= lo2) atomicAdd(&h[(u - lo2) >> 7], 1u);
        }
    }
    if (i < n4) {
        v4u a = in[i];
        #pragma unroll
        for (int k = 0; k < 4; ++k) {
            unsigned u = a[k] & 0x7fffffffu;
            if (u >= hi2) ++above;
            else if (u >= lo2) atomicAdd(&h[(u - lo2) >> 7], 1u);
        }
    }
    red[threadIdx.x] = above;
    __syncthreads();
    for (int s = 128; s > 0; s >>= 1) {
        if (threadIdx.x < (unsigned)s) red[threadIdx.x] += red[threadIdx.x + s];
        __syncthreads();
    }
    if (threadIdx.x == 0 && red[0]) atomicAdd(&res[2], red[0]);
    for (int i2 = threadIdx.x; i2 < NBF2; i2 += blockDim.x) {
        unsigned c = h[i2];
        if (c) atomicAdd(&gh[i2], c);
    }
}

// Walk window2 bins (descending) from countAbove; recover Wh, Wt prefixes -> t^2.
// Same 128-ulp lattice as R3 (lo2 is a multiple of 128 ulp) -> identical t^2.
__global__ void scan_fine(const unsigned* __restrict__ gh, unsigned* __restrict__ res,
                          unsigned need_h, unsigned need_t) {
    __shared__ unsigned bins[NBF2];     // descending-value order
    __shared__ unsigned part[256];
    __shared__ unsigned sup[16];
    unsigned s = 0;
    #pragma unroll
    for (int j = 0; j < 8; ++j) {
        int idx = threadIdx.x * 8 + j;
        unsigned c = gh[NBF2 - 1 - idx];
        bins[idx] = c;
        s += c;
    }
    part[threadIdx.x] = s;
    __syncthreads();
    if (threadIdx.x < 16) {
        unsigned t = 0;
        for (int j = 0; j < 16; ++j) t += part[threadIdx.x * 16 + j];
        sup[threadIdx.x] = t;
    }
    __syncthreads();
    if (threadIdx.x == 0) {
        const unsigned lo2 = (res[0] << 19) + (res[5] << 7);
        const unsigned base = res[2];   // count strictly above window2
        unsigned needs[2] = { need_h, need_t };
        unsigned keys[2];
        for (int q = 0; q < 2; ++q) {
            unsigned accum = base; int sb = 15;
            for (int i = 0; i < 16; ++i) { unsigned nx = accum + sup[i]; if (nx >= needs[q]) { sb = i; break; } accum = nx; }
            int pb = sb * 16 + 15;
            for (int i = sb * 16; i < sb * 16 + 16; ++i) { unsigned nx = accum + part[i]; if (nx >= needs[q]) { pb = i; break; } accum = nx; }
            int d = pb * 8 + 7;
            for (int i = pb * 8; i < pb * 8 + 8; ++i) { unsigned nx = accum + bins[i]; if (nx >= needs[q]) { d = i; break; } accum = nx; }
            keys[q] = (unsigned)(NBF2 - 1 - d);
        }
        float Wh = __uint_as_float(lo2 + (keys[0] << 7) + 64u);   // 128-ulp bin center
        float Wt = __uint_as_float(lo2 + (keys[1] << 7) + 64u);
        float t  = 0.5f * (Wh + Wt);
        res[3] = __float_as_uint(t * t);
    }
}

__global__ void apply_mask(const v4f* __restrict__ in, v4f* __restrict__ out,
                           const unsigned* __restrict__ res, int n4) {
    float t2 = __uint_as_float(res[3]);
    int stride = gridDim.x * blockDim.x;
    for (int i = blockIdx.x * blockDim.x + threadIdx.x; i < n4; i += stride) {
        v4f w = in[i];   // caching load: input is L3-resident after fine_hist
        v4f o;
        // out = w * sigmoid((w^2 - t2)/0.01) = w * rcp(1 + exp((t2 - w^2)*100))
        o.x = w.x * __builtin_amdgcn_rcpf(1.0f + __expf((t2 - w.x * w.x) * 100.0f));
        o.y = w.y * __builtin_amdgcn_rcpf(1.0f + __expf((t2 - w.y * w.y) * 100.0f));
        o.z = w.z * __builtin_amdgcn_rcpf(1.0f + __expf((t2 - w.z * w.z) * 100.0f));
        o.w = w.w * __builtin_amdgcn_rcpf(1.0f + __expf((t2 - w.w * w.w) * 100.0f));
        __builtin_nontemporal_store(o, &out[i]);  // don't evict the input from L3
    }
}

extern "C" void kernel_launch(void* const* d_in, const int* in_sizes, int n_in,
                              void* d_out, int out_size, void* d_ws, size_t ws_size,
                              hipStream_t stream) {
    const int n = in_sizes[0];          // 67108864
    const int n4 = n / 4;
    const v4u* in4 = (const v4u*)d_in[0];

    unsigned* ws      = (unsigned*)d_ws;
    unsigned* hist_s  = ws;                          // 4096   coarse sample hist
    unsigned* hist_sf = ws + NBC;                    // 12288  sample fine hist
    unsigned* hist_f  = ws + NBC + NBSF;             // 2048   full-pass fine hist
    unsigned* res     = ws + NBC + NBSF + NBF2;      // res[0]=b_lo res[1]=b_hi res[2]=countAbove
                                                     // res[3]=t2 res[4]=sampleAbove res[5]=kb

    // Match Python: ind = int((1.0-0.9)*n) - 1; lim = clip(ind, 0, n-2)
    int ind = (int)((1.0 - 0.9) * (double)n) - 1;
    int lim = ind < 0 ? 0 : ind;
    if (lim > n - 2) lim = n - 2;
    unsigned need_h = (unsigned)lim + 1u;   // cumulative-from-top count for Wh
    unsigned need_t = (unsigned)lim + 2u;   // for Wt

    const unsigned SAMPLE = 1024u * 4096u;  // 4M elements
    unsigned sample_need = (unsigned)((double)need_h * (double)SAMPLE / (double)n);
    if (sample_need == 0) sample_need = 1;

    const int nz = NBC + NBSF + NBF2 + 8;
    zero_ws<<<(nz + 255) / 256, 256, 0, stream>>>(ws, nz);
    sample_hist<<<1024, 256, 0, stream>>>(in4, hist_s);
    scan_sample<<<1, 256, 0, stream>>>(hist_s, res, sample_need);
    sample_fine_hist<<<1024, 256, 0, stream>>>(in4, res, hist_sf);
    scan_sample2<<<1, 256, 0, stream>>>(hist_sf, res, sample_need);
    fine_hist<<<4096, 256, 0, stream>>>(in4, res, hist_f, n4);
    scan_fine<<<1, 256, 0, stream>>>(hist_f, res, need_h, need_t);
    apply_mask<<<8192, 256, 0, stream>>>((const v4f*)d_in[0], (v4f*)d_out, res, n4);
}